// Round 25
// baseline (59.989 us; speedup 1.0000x reference)
//
#include <hip/hip_runtime.h>
#include <hip/hip_bf16.h>

#define NB 8192   // B
#define ND 128    // D
#define N2 16384  // 2B

#define CPB 512               // columns per block (32-way column split)
#define CTILE 64              // columns staged per LDS tile
#define NT (CPB / CTILE)      // 8 tiles per block
#define TILEB (CTILE * 128)   // 8192 bytes per fp8 tile

typedef __attribute__((ext_vector_type(4))) float f32x4;
typedef __attribute__((ext_vector_type(16))) float f32x16;
typedef __attribute__((ext_vector_type(4))) int v4i;
typedef __attribute__((ext_vector_type(8))) int v8i;

// sqrt((1/T) * log2(e)) with T=0.5 : sqrt(2.8853900817779268)
static constexpr float SQRT_C_VAL = 1.69864368f;

// ---------------- normalize + pos-dot + fp8 quantize + quantized self-dot ----------------
__global__ __launch_bounds__(256) void nrm_kernel(const float* __restrict__ zi,
                                                  const float* __restrict__ zj,
                                                  unsigned short* __restrict__ reps8_u16,
                                                  float* __restrict__ pos,
                                                  float* __restrict__ ssum,
                                                  float* __restrict__ sdiag,
                                                  float* __restrict__ out) {
    const int gtid = blockIdx.x * 256 + threadIdx.x;
    if (gtid < N2) ssum[gtid] = 0.f;  // replaces the hipMemsetAsync dispatch
    if (gtid == 0) out[0] = 0.f;      // fin_kernel accumulates atomically
    const int pair = gtid >> 6;
    const int lane = threadIdx.x & 63;
    const float2 vi = *reinterpret_cast<const float2*>(zi + pair * ND + lane * 2);
    const float2 vj = *reinterpret_cast<const float2*>(zj + pair * ND + lane * 2);
    float ssi = vi.x * vi.x + vi.y * vi.y;
    float ssj = vj.x * vj.x + vj.y * vj.y;
#pragma unroll
    for (int m = 1; m < 64; m <<= 1) {
        ssi += __shfl_xor(ssi, m);
        ssj += __shfl_xor(ssj, m);
    }
    float ni = fmaxf(sqrtf(ssi), 1e-12f);
    float nj = fmaxf(sqrtf(ssj), 1e-12f);
    const float ii = 1.0f / ni, ij = 1.0f / nj;
    const float uix = vi.x * ii, uiy = vi.y * ii;
    const float ujx = vj.x * ij, ujy = vj.y * ij;
    float d = uix * ujx + uiy * ujy;
#pragma unroll
    for (int m = 1; m < 64; m <<= 1) d += __shfl_xor(d, m);
    if (lane == 0) pos[pair] = d;
    // fp8 e4m3 (OCP on gfx950), pre-scaled by sqrt(C) so MFMA output = sim * C = exp2 arg
    const int pki = __builtin_amdgcn_cvt_pk_fp8_f32(uix * SQRT_C_VAL, uiy * SQRT_C_VAL, 0, false);
    const int pkj = __builtin_amdgcn_cvt_pk_fp8_f32(ujx * SQRT_C_VAL, ujy * SQRT_C_VAL, 0, false);
    reps8_u16[pair * 64 + lane] = (unsigned short)(pki & 0xFFFF);
    reps8_u16[(NB + pair) * 64 + lane] = (unsigned short)(pkj & 0xFFFF);
    // quantized self-dot (== MFMA diagonal term, exact): fin subtracts exp2(sdiag)
    const float fi0 = __builtin_amdgcn_cvt_f32_fp8(pki, 0);
    const float fi1 = __builtin_amdgcn_cvt_f32_fp8(pki, 1);
    const float fj0 = __builtin_amdgcn_cvt_f32_fp8(pkj, 0);
    const float fj1 = __builtin_amdgcn_cvt_f32_fp8(pkj, 1);
    float sqi = fi0 * fi0 + fi1 * fi1;
    float sqj = fj0 * fj0 + fj1 * fj1;
#pragma unroll
    for (int m = 1; m < 64; m <<= 1) {
        sqi += __shfl_xor(sqi, m);
        sqj += __shfl_xor(sqj, m);
    }
    if (lane == 0) {
        sdiag[pair] = sqi;
        sdiag[NB + pair] = sqj;
    }
}

// ---------------- fused sim-GEMM (MX-fp8, 32x32x64) + sum(exp2) ----------------
__device__ inline void gload_lds16(const void* g, void* l) {
    __builtin_amdgcn_global_load_lds(
        (const __attribute__((address_space(1))) void*)g,
        (__attribute__((address_space(3))) void*)l, 16, 0, 0);
}

// LDS tile: 32 macro-rows x 256 B (16 slots of 16 B). Macro-row m holds cols {2m,2m+1};
// stored slot sp = s ^ ((m&3)<<1), where s = 2*chunk + (col&1). Involution => stage
// (via pre-swizzled global source, rule #21) and read use the same XOR.
// R24 NaN lesson: sibling slots are SLOT XORs — (sA^2)*16, NEVER byte +32 (carry when
// sA bit1=1). +128 (slot ^8) is safe as addition only because sA bit3 == 0 provably.
__global__ __launch_bounds__(512, 2) void sim_kernel(const char* __restrict__ reps8,
                                                     float* __restrict__ ssum) {
    __shared__ __align__(16) char lds[4][TILEB];  // 4 x 8 KiB ring
    const int tid = threadIdx.x;
    const int lane = tid & 63;
    const int wid = tid >> 6;       // 0..7
    const int l31 = lane & 31;
    const int h5 = lane >> 5;       // K-chunk selector
    const int rb = blockIdx.x * 256;  // 256 rows per block (8 waves x 32)
    const int cb = blockIdx.y * CPB;  // column split
    const int qb = rb + wid * 32;     // this wave's 32 rows

    // Q fragments (A, 32x32x64): lane row = qb + l31, K-chunks [32*h5,+32) and [64+32*h5,+32)
    v8i qfA = *reinterpret_cast<const v8i*>(reps8 + (size_t)(qb + l31) * 128 + h5 * 32);
    v8i qfB = *reinterpret_cast<const v8i*>(reps8 + (size_t)(qb + l31) * 128 + 64 + h5 * 32);
    // drain Q loads so vmcnt counts only staging loads from here on
    __builtin_amdgcn_sched_barrier(0);
    asm volatile("s_waitcnt vmcnt(0)" ::: "memory");
    __builtin_amdgcn_sched_barrier(0);

    f32x16 sacc;
#pragma unroll
    for (int r = 0; r < 16; ++r) sacc[r] = 0.f;

    // tile-invariant per-lane staging source (1 slot of 16 B per thread)
    const int m_s = tid >> 4;                 // macro-row 0..31
    const int sp_s = tid & 15;                // stored slot
    const int s_s = sp_s ^ ((m_s & 3) << 1);  // pre-swizzle slot (involution)
    const char* srcq = reps8 + (size_t)(cb + 2 * m_s + (s_s & 1)) * 128 + (s_s >> 1) * 16;

    auto stage = [&](int t) {
        char* dst = &lds[t & 3][wid * 1024];  // wave-uniform base
        gload_lds16(srcq + (size_t)t * TILEB, dst);
    };

    // per-lane ds_read offsets (cg-invariant): macro-row w = l31>>1 within cg half
    const int w = l31 >> 1;
    const int sA = (4 * h5 + (l31 & 1)) ^ ((w & 3) << 1);  // slot of K-chunk 2*h5
    const int rdLo = w * 256 + sA * 16;                    // chunk 2*h5
    const int rdHi = w * 256 + (sA ^ 2) * 16;              // chunk 2*h5+1 (slot XOR!)

    // prologue: 3 tiles in flight (3 loads/wave)
    stage(0);
    stage(1);
    stage(2);

#pragma unroll 1  // R18 lesson: full unroll software-pipelines all tiles -> spill
    for (int t = 0; t < NT; ++t) {
        // counted wait for tile t (per-wave own loads: 1/tile), then ONE barrier per tile
        if (t <= NT - 3) {
            asm volatile("s_waitcnt vmcnt(2)" ::: "memory");
        } else if (t == NT - 2) {
            asm volatile("s_waitcnt vmcnt(1)" ::: "memory");
        } else {
            asm volatile("s_waitcnt vmcnt(0)" ::: "memory");
        }
        __builtin_amdgcn_s_barrier();  // all waves' tile-t loads landed; compute(t-1) done
        if (t + 3 < NT) stage(t + 3);  // overwrites buf[(t-1)&3], safe after barrier

        const char* lbase = lds[t & 3];
        // 2 col-groups of 32 cols; order rotated per wave to desync pipe phases
#pragma unroll
        for (int cc = 0; cc < 2; ++cc) {
            const int cg = (cc + wid) & 1;
            const char* cgb = lbase + cg * 4096;
            const v4i a0 = *reinterpret_cast<const v4i*>(cgb + rdLo);
            const v4i a1 = *reinterpret_cast<const v4i*>(cgb + rdHi);
            const v4i b0 = *reinterpret_cast<const v4i*>(cgb + rdLo + 128);  // slot ^8: bit3==0
            const v4i b1 = *reinterpret_cast<const v4i*>(cgb + rdHi + 128);
            const v8i kfA = __builtin_shufflevector(a0, a1, 0, 1, 2, 3, 4, 5, 6, 7);
            const v8i kfB = __builtin_shufflevector(b0, b1, 0, 1, 2, 3, 4, 5, 6, 7);
            f32x16 acc;
#pragma unroll
            for (int r = 0; r < 16; ++r) acc[r] = 0.f;
            __builtin_amdgcn_s_setprio(1);
            acc = __builtin_amdgcn_mfma_scale_f32_32x32x64_f8f6f4(
                qfA, kfA, acc, 0, 0, 0, 0x7F7F7F7F, 0, 0x7F7F7F7F);
            acc = __builtin_amdgcn_mfma_scale_f32_32x32x64_f8f6f4(
                qfB, kfB, acc, 0, 0, 0, 0x7F7F7F7F, 0, 0x7F7F7F7F);
            __builtin_amdgcn_s_setprio(0);
            f32x16 e;
#pragma unroll
            for (int r = 0; r < 16; ++r) e[r] = __builtin_amdgcn_exp2f(acc[r]);
            sacc += e;  // packed f32 adds
        }
    }

    // row sums: reduce across the 32 column-lanes (l31), then flush
#pragma unroll
    for (int r = 0; r < 16; ++r) {
#pragma unroll
        for (int m = 1; m < 32; m <<= 1) sacc[r] += __shfl_xor(sacc[r], m);
    }
    if (l31 == 0) {
        // lane holds 16 rows: row = qb + (r&3) + 8*(r>>2) + 4*h5
#pragma unroll
        for (int r = 0; r < 16; ++r)
            atomicAdd(&ssum[qb + (r & 3) + 8 * (r >> 2) + 4 * h5], sacc[r]);
    }
}

// ---------------- finalize: loss = mean(ln(ssum - exp2(sdiag)) - 2*pos), distributed ----------------
__global__ __launch_bounds__(1024) void fin_kernel(const float* __restrict__ ssum,
                                                   const float* __restrict__ pos,
                                                   const float* __restrict__ sdiag,
                                                   float* __restrict__ out) {
    const int tid = threadIdx.x;
    const int r0 = blockIdx.x * (N2 / 16);  // 16 blocks x 1024 rows
    float acc = 0.f;
    for (int i = tid; i < N2 / 16; i += 1024) {
        const int r = r0 + i;
        const int p = (r < NB) ? r : r - NB;
        acc += logf(ssum[r] - exp2f(sdiag[r])) - 2.0f * pos[p];
    }
#pragma unroll
    for (int m = 1; m < 64; m <<= 1) acc += __shfl_xor(acc, m);
    __shared__ float red[16];
    const int wid = tid >> 6, lane = tid & 63;
    if (lane == 0) red[wid] = acc;
    __syncthreads();
    if (wid == 0) {
        float v = (lane < 16) ? red[lane] : 0.f;
#pragma unroll
        for (int m = 1; m < 16; m <<= 1) v += __shfl_xor(v, m);
        if (lane == 0) atomicAdd(out, v / (float)N2);
    }
}

extern "C" void kernel_launch(void* const* d_in, const int* in_sizes, int n_in,
                              void* d_out, int out_size, void* d_ws, size_t ws_size,
                              hipStream_t stream) {
    const float* zi = (const float*)d_in[0];
    const float* zj = (const float*)d_in[1];
    float* out = (float*)d_out;
    char* ws = (char*)d_ws;

    char* reps8 = ws;                                      // 16384*128 = 2 MiB fp8
    float* pos = (float*)(ws + (size_t)N2 * ND);           // 8192 f32
    float* ssum = pos + NB;                                // 16384 f32
    float* sdiag = ssum + N2;                              // 16384 f32

    nrm_kernel<<<NB / 4, 256, 0, stream>>>(zi, zj, (unsigned short*)reps8, pos, ssum, sdiag, out);
    dim3 grid(N2 / 256, N2 / CPB);
    sim_kernel<<<grid, 512, 0, stream>>>(reps8, ssum);
    fin_kernel<<<16, 1024, 0, stream>>>(ssum, pos, sdiag, out);
}

// Round 26
// 53.653 us; speedup vs baseline: 1.1181x; 1.1181x over previous
//
#include <hip/hip_runtime.h>
#include <hip/hip_bf16.h>

#define NB 8192   // B
#define ND 128    // D
#define N2 16384  // 2B

#define CPB 512               // columns per block (32-way column split)
#define CTILE 64              // columns staged per LDS tile
#define NT (CPB / CTILE)      // 8 tiles per block
#define TILEB (CTILE * 128)   // 8192 bytes per fp8 tile

typedef __attribute__((ext_vector_type(4))) float f32x4;
typedef __attribute__((ext_vector_type(4))) int v4i;
typedef __attribute__((ext_vector_type(8))) int v8i;

// sqrt((1/T) * log2(e)) with T=0.5 : sqrt(2.8853900817779268)
static constexpr float SQRT_C_VAL = 1.69864368f;

// ---------------- normalize + pos-dot + fp8 quantize + quantized self-dot ----------------
__global__ __launch_bounds__(256) void nrm_kernel(const float* __restrict__ zi,
                                                  const float* __restrict__ zj,
                                                  unsigned short* __restrict__ reps8_u16,
                                                  float* __restrict__ pos,
                                                  float* __restrict__ ssum,
                                                  float* __restrict__ sdiag,
                                                  float* __restrict__ out) {
    const int gtid = blockIdx.x * 256 + threadIdx.x;
    if (gtid < N2) ssum[gtid] = 0.f;  // replaces the hipMemsetAsync dispatch
    if (gtid == 0) out[0] = 0.f;      // fin_kernel accumulates atomically
    const int pair = gtid >> 6;
    const int lane = threadIdx.x & 63;
    const float2 vi = *reinterpret_cast<const float2*>(zi + pair * ND + lane * 2);
    const float2 vj = *reinterpret_cast<const float2*>(zj + pair * ND + lane * 2);
    float ssi = vi.x * vi.x + vi.y * vi.y;
    float ssj = vj.x * vj.x + vj.y * vj.y;
#pragma unroll
    for (int m = 1; m < 64; m <<= 1) {
        ssi += __shfl_xor(ssi, m);
        ssj += __shfl_xor(ssj, m);
    }
    float ni = fmaxf(sqrtf(ssi), 1e-12f);
    float nj = fmaxf(sqrtf(ssj), 1e-12f);
    const float ii = 1.0f / ni, ij = 1.0f / nj;
    const float uix = vi.x * ii, uiy = vi.y * ii;
    const float ujx = vj.x * ij, ujy = vj.y * ij;
    float d = uix * ujx + uiy * ujy;
#pragma unroll
    for (int m = 1; m < 64; m <<= 1) d += __shfl_xor(d, m);
    if (lane == 0) pos[pair] = d;
    // fp8 e4m3 (OCP on gfx950), pre-scaled by sqrt(C) so MFMA output = sim * C = exp2 arg
    const int pki = __builtin_amdgcn_cvt_pk_fp8_f32(uix * SQRT_C_VAL, uiy * SQRT_C_VAL, 0, false);
    const int pkj = __builtin_amdgcn_cvt_pk_fp8_f32(ujx * SQRT_C_VAL, ujy * SQRT_C_VAL, 0, false);
    reps8_u16[pair * 64 + lane] = (unsigned short)(pki & 0xFFFF);
    reps8_u16[(NB + pair) * 64 + lane] = (unsigned short)(pkj & 0xFFFF);
    // quantized self-dot (== MFMA diagonal term, exact): fin subtracts exp2(sdiag)
    const float fi0 = __builtin_amdgcn_cvt_f32_fp8(pki, 0);
    const float fi1 = __builtin_amdgcn_cvt_f32_fp8(pki, 1);
    const float fj0 = __builtin_amdgcn_cvt_f32_fp8(pkj, 0);
    const float fj1 = __builtin_amdgcn_cvt_f32_fp8(pkj, 1);
    float sqi = fi0 * fi0 + fi1 * fi1;
    float sqj = fj0 * fj0 + fj1 * fj1;
#pragma unroll
    for (int m = 1; m < 64; m <<= 1) {
        sqi += __shfl_xor(sqi, m);
        sqj += __shfl_xor(sqj, m);
    }
    if (lane == 0) {
        sdiag[pair] = sqi;
        sdiag[NB + pair] = sqj;
    }
}

// ---------------- fused sim-GEMM (MX-fp8 K=128) + sum(exp2), phase-desynced waves ----------------
__device__ inline void gload_lds16(const void* g, void* l) {
    __builtin_amdgcn_global_load_lds(
        (const __attribute__((address_space(1))) void*)g,
        (__attribute__((address_space(3))) void*)l, 16, 0, 0);
}

// LDS tile: 32 macro-rows x 256 B (16 slots of 16 B). Macro-row m holds cols {2m,2m+1};
// stored slot sp = s ^ ((m&3)<<1), where s = 2*chunk + (col&1). Involution => stage
// (via pre-swizzled global source, rule #21) and read use the same XOR.
__global__ __launch_bounds__(512, 4) void sim_kernel(const char* __restrict__ reps8,
                                                     float* __restrict__ ssum) {
    __shared__ __align__(16) char lds[4][TILEB];  // 4 x 8 KiB ring
    const int tid = threadIdx.x;
    const int lane = tid & 63;
    const int wid = tid >> 6;       // 0..7
    const int l15 = lane & 15;
    const int l4 = lane >> 4;
    const int rb = blockIdx.x * 256;  // 256 rows per block (8 waves x 32)
    const int cb = blockIdx.y * CPB;  // column split
    const int qb = rb + wid * 32;     // this wave's 32 rows

    // Q fragments: per lane row (qb+g*16+l15), contiguous 32 fp8 at k = 32*l4
    v8i qf[2];
#pragma unroll
    for (int g = 0; g < 2; ++g)
        qf[g] = *reinterpret_cast<const v8i*>(
            reps8 + (size_t)(qb + g * 16 + l15) * 128 + l4 * 32);
    // drain Q loads so vmcnt counts only staging loads from here on
    __builtin_amdgcn_sched_barrier(0);
    asm volatile("s_waitcnt vmcnt(0)" ::: "memory");
    __builtin_amdgcn_sched_barrier(0);

    f32x4 sacc[2];
#pragma unroll
    for (int g = 0; g < 2; ++g) sacc[g] = {0.f, 0.f, 0.f, 0.f};

    // tile-invariant per-lane staging source (1 slot of 16 B per thread)
    const int m_s = tid >> 4;                 // macro-row 0..31
    const int sp_s = tid & 15;                // stored slot
    const int s_s = sp_s ^ ((m_s & 3) << 1);  // pre-swizzle slot (involution)
    const char* srcq = reps8 + (size_t)(cb + 2 * m_s + (s_s & 1)) * 128 + (s_s >> 1) * 16;

    auto stage = [&](int t) {
        char* dst = &lds[t & 3][wid * 1024];  // wave-uniform base
        gload_lds16(srcq + (size_t)t * TILEB, dst);
    };

    // per-lane ds_read offsets (cg-invariant): macro-row m = cg*8 + h, h = l15>>1
    const int h = l15 >> 1;
    const int sloA = (4 * l4 + (l15 & 1)) ^ ((h & 3) << 1);
    const int rdlo = h * 256 + sloA * 16;         // slot sloA   (chunk 2*l4)
    const int rdhi = h * 256 + (sloA ^ 2) * 16;   // slot sloA^2 (chunk 2*l4+1)

    // prologue: 3 tiles in flight (3 loads/wave)
    stage(0);
    stage(1);
    stage(2);

#pragma unroll 1  // R18 lesson: full unroll software-pipelines all tiles -> spill
    for (int t = 0; t < NT; ++t) {
        // counted wait for tile t (per-wave own loads: 1/tile), then ONE barrier per tile
        if (t <= NT - 3) {
            asm volatile("s_waitcnt vmcnt(2)" ::: "memory");
        } else if (t == NT - 2) {
            asm volatile("s_waitcnt vmcnt(1)" ::: "memory");
        } else {
            asm volatile("s_waitcnt vmcnt(0)" ::: "memory");
        }
        __builtin_amdgcn_s_barrier();  // all waves' tile-t loads landed; compute(t-1) done
        if (t + 3 < NT) stage(t + 3);  // overwrites buf[(t-1)&3], safe after barrier

        const char* lbase = lds[t & 3];
        // uniform compute; cg order rotated per wave (wid) to desync pipe phases
#pragma unroll
        for (int cc = 0; cc < 4; ++cc) {
            const int cg = (cc + wid) & 3;
            const v4i lo = *reinterpret_cast<const v4i*>(lbase + rdlo + cg * 2048);
            const v4i hi = *reinterpret_cast<const v4i*>(lbase + rdhi + cg * 2048);
            const v8i kf = __builtin_shufflevector(lo, hi, 0, 1, 2, 3, 4, 5, 6, 7);
            const f32x4 z4 = {0.f, 0.f, 0.f, 0.f};
            __builtin_amdgcn_s_setprio(1);
            f32x4 acc0 = __builtin_amdgcn_mfma_scale_f32_16x16x128_f8f6f4(
                qf[0], kf, z4, 0, 0, 0, 0x7F7F7F7F, 0, 0x7F7F7F7F);
            f32x4 acc1 = __builtin_amdgcn_mfma_scale_f32_16x16x128_f8f6f4(
                qf[1], kf, z4, 0, 0, 0, 0x7F7F7F7F, 0, 0x7F7F7F7F);
            __builtin_amdgcn_s_setprio(0);
            f32x4 e0, e1;
#pragma unroll
            for (int r = 0; r < 4; ++r) {
                e0[r] = __builtin_amdgcn_exp2f(acc0[r]);
                e1[r] = __builtin_amdgcn_exp2f(acc1[r]);
            }
            sacc[0] += e0;  // vector adds -> v_pk_add_f32 (half the add issue)
            sacc[1] += e1;
        }
    }

    // reduce across the 16 column-lanes, then one atomic per row
#pragma unroll
    for (int g = 0; g < 2; ++g) {
#pragma unroll
        for (int r = 0; r < 4; ++r) {
#pragma unroll
            for (int m = 1; m < 16; m <<= 1) sacc[g][r] += __shfl_xor(sacc[g][r], m);
        }
    }
    if (l15 == 0) {
#pragma unroll
        for (int g = 0; g < 2; ++g)
#pragma unroll
            for (int r = 0; r < 4; ++r)
                atomicAdd(&ssum[qb + g * 16 + l4 * 4 + r], sacc[g][r]);
    }
}

// ---------------- finalize: loss = mean(ln(ssum - exp2(sdiag)) - 2*pos), distributed ----------------
__global__ __launch_bounds__(1024) void fin_kernel(const float* __restrict__ ssum,
                                                   const float* __restrict__ pos,
                                                   const float* __restrict__ sdiag,
                                                   float* __restrict__ out) {
    const int tid = threadIdx.x;
    const int r0 = blockIdx.x * (N2 / 16);  // 16 blocks x 1024 rows
    float acc = 0.f;
    for (int i = tid; i < N2 / 16; i += 1024) {
        const int r = r0 + i;
        const int p = (r < NB) ? r : r - NB;
        acc += logf(ssum[r] - exp2f(sdiag[r])) - 2.0f * pos[p];
    }
#pragma unroll
    for (int m = 1; m < 64; m <<= 1) acc += __shfl_xor(acc, m);
    __shared__ float red[16];
    const int wid = tid >> 6, lane = tid & 63;
    if (lane == 0) red[wid] = acc;
    __syncthreads();
    if (wid == 0) {
        float v = (lane < 16) ? red[lane] : 0.f;
#pragma unroll
        for (int m = 1; m < 16; m <<= 1) v += __shfl_xor(v, m);
        if (lane == 0) atomicAdd(out, v / (float)N2);
    }
}

extern "C" void kernel_launch(void* const* d_in, const int* in_sizes, int n_in,
                              void* d_out, int out_size, void* d_ws, size_t ws_size,
                              hipStream_t stream) {
    const float* zi = (const float*)d_in[0];
    const float* zj = (const float*)d_in[1];
    float* out = (float*)d_out;
    char* ws = (char*)d_ws;

    char* reps8 = ws;                                      // 16384*128 = 2 MiB fp8
    float* pos = (float*)(ws + (size_t)N2 * ND);           // 8192 f32
    float* ssum = pos + NB;                                // 16384 f32
    float* sdiag = ssum + N2;                              // 16384 f32

    nrm_kernel<<<NB / 4, 256, 0, stream>>>(zi, zj, (unsigned short*)reps8, pos, ssum, sdiag, out);
    dim3 grid(N2 / 256, N2 / CPB);
    sim_kernel<<<grid, 512, 0, stream>>>(reps8, ssum);
    fin_kernel<<<16, 1024, 0, stream>>>(ssum, pos, sdiag, out);
}